// Round 3
// baseline (29728.445 us; speedup 1.0000x reference)
//
#include <hip/hip_runtime.h>
#include <hip/hip_bf16.h>
#include <math.h>

#define VDIM 128
#define HDIM 512
#define BATCH 512
#define RPB 4                  // batch rows per block
#define CPT 4                  // columns per thread
#define CG (HDIM / CPT)        // 128 col-groups per row
#define NT (RPB * CG)          // 512 threads (8 waves; each wave = one row's half)
#define NBLK (BATCH / RPB)     // 128 blocks
#define NWAVE (NT / 64)
#define LN_EPS 1e-5f

struct Params {
    const float *u;
    const float *q_w1, *q_b1, *q_g1, *q_be1;
    const float *q_w2, *q_b2, *q_g2, *q_be2;
    const float *q_w3, *q_b3, *q_g3, *q_be3;
    const float *q_W, *q_bias, *q_marg;
    const float *f_w1, *f_b1, *f_g1, *f_be1;
    const float *f_w2, *f_b2, *f_g2, *f_be2;
    const float *f_w3, *f_b3, *f_g3, *f_be3;
    const float *f_w4, *f_b4, *J;
    const int *top_order, *pa_mask;
    float *V_out, *lp, *lf, *score, *loss;
};

// Deterministic reduction over one row's 128 threads (= waves 2r and 2r+1).
// All NT threads must call (uniform control flow).
__device__ __forceinline__ float row_reduce(float v, float *red, int tid, int r) {
#pragma unroll
    for (int off = 1; off < 64; off <<= 1) v += __shfl_xor(v, off, 64);
    if ((tid & 63) == 0) red[tid >> 6] = v;
    __syncthreads();
    float s = red[2 * r] + red[2 * r + 1];
    __syncthreads();
    return s;
}

__device__ __forceinline__ float block_reduce1(float v, float *red, int tid) {
#pragma unroll
    for (int off = 1; off < 64; off <<= 1) v += __shfl_xor(v, off, 64);
    if ((tid & 63) == 0) red[tid >> 6] = v;
    __syncthreads();
    float s = 0.f;
#pragma unroll
    for (int w = 0; w < NWAVE; ++w) s += red[w];
    __syncthreads();
    return s;
}

// Orow[4cg..4cg+3] = relu(LN(Arow @ W + b) * g + be) for one row.
// Arow: LDS [K] floats (this row's activations). W: global [K][HDIM].
// Thread handles columns 4cg..4cg+3. 1 LDS b128 per 4-k tile (broadcast),
// 4 coalesced global float4 loads, 16 FMAs.
template <int K>
__device__ __forceinline__ void gemv_ln(const float *__restrict__ Arow,
                                        const float *__restrict__ W,
                                        const float *__restrict__ bias,
                                        const float *__restrict__ gam,
                                        const float *__restrict__ bet,
                                        float *__restrict__ Orow,
                                        float *red, int tid, int r, int cg) {
    const float4 *Wv = (const float4 *)W + cg;    // column block 4cg..4cg+3
    const float4 *Av = (const float4 *)Arow;
    float4 acc = make_float4(0.f, 0.f, 0.f, 0.f);
#pragma unroll 4
    for (int k4 = 0; k4 < K / 4; ++k4) {
        float4 a  = Av[k4];                        // LDS b128, wave-uniform broadcast
        float4 w0 = Wv[(size_t)(4 * k4 + 0) * CG]; // 1KB/wave coalesced
        float4 w1 = Wv[(size_t)(4 * k4 + 1) * CG];
        float4 w2 = Wv[(size_t)(4 * k4 + 2) * CG];
        float4 w3 = Wv[(size_t)(4 * k4 + 3) * CG];
        acc.x = fmaf(a.x, w0.x, acc.x); acc.y = fmaf(a.x, w0.y, acc.y);
        acc.z = fmaf(a.x, w0.z, acc.z); acc.w = fmaf(a.x, w0.w, acc.w);
        acc.x = fmaf(a.y, w1.x, acc.x); acc.y = fmaf(a.y, w1.y, acc.y);
        acc.z = fmaf(a.y, w1.z, acc.z); acc.w = fmaf(a.y, w1.w, acc.w);
        acc.x = fmaf(a.z, w2.x, acc.x); acc.y = fmaf(a.z, w2.y, acc.y);
        acc.z = fmaf(a.z, w2.z, acc.z); acc.w = fmaf(a.z, w2.w, acc.w);
        acc.x = fmaf(a.w, w3.x, acc.x); acc.y = fmaf(a.w, w3.y, acc.y);
        acc.z = fmaf(a.w, w3.z, acc.z); acc.w = fmaf(a.w, w3.w, acc.w);
    }
    float4 b4 = ((const float4 *)bias)[cg];
    acc.x += b4.x; acc.y += b4.y; acc.z += b4.z; acc.w += b4.w;

    // two-pass LN over this row's 512 columns
    const float inv = 1.f / (float)HDIM;
    float m = row_reduce(acc.x + acc.y + acc.z + acc.w, red, tid, r) * inv;
    float4 d = make_float4(acc.x - m, acc.y - m, acc.z - m, acc.w - m);
    float var = row_reduce(d.x * d.x + d.y * d.y + d.z * d.z + d.w * d.w,
                           red, tid, r) * inv;
    float rs = 1.f / sqrtf(var + LN_EPS);
    float4 g4 = ((const float4 *)gam)[cg];
    float4 e4 = ((const float4 *)bet)[cg];
    float4 h;
    h.x = fmaxf(fmaf(d.x * rs, g4.x, e4.x), 0.f);
    h.y = fmaxf(fmaf(d.y * rs, g4.y, e4.y), 0.f);
    h.z = fmaxf(fmaf(d.z * rs, g4.z, e4.z), 0.f);
    h.w = fmaxf(fmaf(d.w * rs, g4.w, e4.w), 0.f);
    ((float4 *)Orow)[cg] = h;
    __syncthreads();
}

__global__ __launch_bounds__(NT) void gfn_scan(Params P) {
    __shared__ float V[RPB][VDIM];     // current state, one row per 2 waves
    __shared__ float VP[RPB][VDIM];    // masked parents
    __shared__ float HA[RPB][HDIM];
    __shared__ float HB[RPB][HDIM];
    __shared__ float red[NWAVE];

    const int tid = threadIdx.x;
    const int r = tid >> 7;            // row 0..3  (wave-uniform)
    const int cg = tid & (CG - 1);     // col-group 0..127
    const int row0 = blockIdx.x * RPB;

    V[r][cg] = 0.f;                    // cg spans 0..127 == VDIM
    __syncthreads();

    for (int i = 0; i < VDIM; ++i) {
        const int node = P.top_order[i];

        // V_pa = V * mask_row(node); abs-sum for the empty check (k = cg)
        float mk = (float)P.pa_mask[node * VDIM + cg];
        float vp = V[r][cg] * mk;
        VP[r][cg] = vp;
        float asum = row_reduce(fabsf(vp), red, tid, r);  // syncs make VP visible

        // qtrunk
        gemv_ln<VDIM>(&VP[r][0], P.q_w1, P.q_b1, P.q_g1, P.q_be1, &HA[r][0], red, tid, r, cg);
        gemv_ln<HDIM>(&HA[r][0], P.q_w2, P.q_b2, P.q_g2, P.q_be2, &HB[r][0], red, tid, r, cg);
        gemv_ln<HDIM>(&HB[r][0], P.q_w3, P.q_b3, P.q_g3, P.q_be3, &HA[r][0], red, tid, r, cg);

        // head: x = h3 . q_W[node] (+ bias later)
        float4 h3 = ((float4 *)&HA[r][0])[cg];
        float4 wq = ((const float4 *)(P.q_W + (size_t)node * HDIM))[cg];
        float x = row_reduce(h3.x * wq.x + h3.y * wq.y + h3.z * wq.z + h3.w * wq.w,
                             red, tid, r);

        if (cg == 0) {
            float xr = x + P.q_bias[node];
            float arg = (asum == 0.f) ? P.q_marg[node] : xr;   // empty -> marginal
            float p = 1.f / (1.f + expf(-arg));
            float uv = P.u[i * BATCH + row0 + r];              // u indexed by step i
            bool samp = uv < p;
            V[r][node] = samp ? 1.f : -1.f;                    // scatter into column
            P.lp[i * BATCH + row0 + r] = samp ? logf(p) : log1pf(-p);
        }
        __syncthreads();

        // fnet(V_new)
        gemv_ln<VDIM>(&V[r][0],  P.f_w1, P.f_b1, P.f_g1, P.f_be1, &HB[r][0], red, tid, r, cg);
        gemv_ln<HDIM>(&HB[r][0], P.f_w2, P.f_b2, P.f_g2, P.f_be2, &HA[r][0], red, tid, r, cg);
        gemv_ln<HDIM>(&HA[r][0], P.f_w3, P.f_b3, P.f_g3, P.f_be3, &HB[r][0], red, tid, r, cg);

        float4 hf = ((float4 *)&HB[r][0])[cg];
        float4 w4 = ((const float4 *)P.f_w4)[cg];
        float lfv = row_reduce(hf.x * w4.x + hf.y * w4.y + hf.z * w4.z + hf.w * w4.w,
                               red, tid, r);
        if (cg == 0) P.lf[i * BATCH + row0 + r] = lfv + P.f_b4[0];
        // row_reduce ended with __syncthreads(); V stable for next iteration
    }

    // terminal score: V[r] . J . V[r]  (thread owns jj = cg)
    float inner = 0.f;
#pragma unroll 4
    for (int ii = 0; ii < VDIM; ++ii)
        inner = fmaf(V[r][ii], P.J[(size_t)ii * VDIM + cg], inner);
    float sc = row_reduce(inner * V[r][cg], red, tid, r);
    if (cg == 0) P.score[row0 + r] = sc;

    // write V out (coalesced per row)
    P.V_out[(size_t)(row0 + r) * VDIM + cg] = V[r][cg];
}

// One block: F0 = fnet(0), then assemble log_flow and reduce the loss.
__global__ __launch_bounds__(NT) void gfn_loss(Params P) {
    __shared__ float H1[HDIM], H2[HDIM];
    __shared__ float red1[NWAVE];
    const int tid = threadIdx.x;
    const float inv = 1.f / (float)HDIM;

    // F0 = fnet(zeros): layer1 input is 0 -> z = b1
    float z = P.f_b1[tid];
    float m = block_reduce1(z, red1, tid) * inv;
    float d = z - m;
    float var = block_reduce1(d * d, red1, tid) * inv;
    float h = fmaxf(fmaf(d * (1.f / sqrtf(var + LN_EPS)), P.f_g1[tid], P.f_be1[tid]), 0.f);
    H1[tid] = h;
    __syncthreads();

    float acc = 0.f;
    for (int k = 0; k < HDIM; ++k) acc = fmaf(H1[k], P.f_w2[(size_t)k * HDIM + tid], acc);
    z = acc + P.f_b2[tid];
    m = block_reduce1(z, red1, tid) * inv;
    d = z - m;
    var = block_reduce1(d * d, red1, tid) * inv;
    h = fmaxf(fmaf(d * (1.f / sqrtf(var + LN_EPS)), P.f_g2[tid], P.f_be2[tid]), 0.f);
    H2[tid] = h;
    __syncthreads();

    acc = 0.f;
    for (int k = 0; k < HDIM; ++k) acc = fmaf(H2[k], P.f_w3[(size_t)k * HDIM + tid], acc);
    z = acc + P.f_b3[tid];
    m = block_reduce1(z, red1, tid) * inv;
    d = z - m;
    var = block_reduce1(d * d, red1, tid) * inv;
    h = fmaxf(fmaf(d * (1.f / sqrtf(var + LN_EPS)), P.f_g3[tid], P.f_be3[tid]), 0.f);
    float F0 = block_reduce1(h * P.f_w4[tid], red1, tid) + P.f_b4[0];

    // loss: thread tid owns batch element b = tid
    const int b = tid;
    float lfp = F0;
    float s = 0.f;
    for (int t = 0; t < VDIM; ++t) {
        float lp = P.lp[t * BATCH + b];
        float lfn = (t == VDIM - 1) ? P.score[b] : P.lf[t * BATCH + b];
        float dd = lfp + lp - lfn;
        s = fmaf(dd, dd, s);
        lfp = lfn;
    }
    s *= (1.f / (float)VDIM);
    float total = block_reduce1(s, red1, tid) * (1.f / (float)BATCH);
    if (tid == 0) P.loss[0] = total;
}

extern "C" void kernel_launch(void *const *d_in, const int *in_sizes, int n_in,
                              void *d_out, int out_size, void *d_ws, size_t ws_size,
                              hipStream_t stream) {
    Params P;
    P.u     = (const float *)d_in[0];
    P.q_w1  = (const float *)d_in[1];
    P.q_b1  = (const float *)d_in[2];
    P.q_g1  = (const float *)d_in[3];
    P.q_be1 = (const float *)d_in[4];
    P.q_w2  = (const float *)d_in[5];
    P.q_b2  = (const float *)d_in[6];
    P.q_g2  = (const float *)d_in[7];
    P.q_be2 = (const float *)d_in[8];
    P.q_w3  = (const float *)d_in[9];
    P.q_b3  = (const float *)d_in[10];
    P.q_g3  = (const float *)d_in[11];
    P.q_be3 = (const float *)d_in[12];
    P.q_W   = (const float *)d_in[13];
    P.q_bias= (const float *)d_in[14];
    P.q_marg= (const float *)d_in[15];
    P.f_w1  = (const float *)d_in[16];
    P.f_b1  = (const float *)d_in[17];
    P.f_g1  = (const float *)d_in[18];
    P.f_be1 = (const float *)d_in[19];
    P.f_w2  = (const float *)d_in[20];
    P.f_b2  = (const float *)d_in[21];
    P.f_g2  = (const float *)d_in[22];
    P.f_be2 = (const float *)d_in[23];
    P.f_w3  = (const float *)d_in[24];
    P.f_b3  = (const float *)d_in[25];
    P.f_g3  = (const float *)d_in[26];
    P.f_be3 = (const float *)d_in[27];
    P.f_w4  = (const float *)d_in[28];
    P.f_b4  = (const float *)d_in[29];
    P.J     = (const float *)d_in[30];
    P.top_order = (const int *)d_in[31];
    P.pa_mask   = (const int *)d_in[32];

    float *ws = (float *)d_ws;
    P.V_out = (float *)d_out;
    P.loss  = (float *)d_out + (size_t)BATCH * VDIM;   // d_out[65536]
    P.lp    = ws;                                      // [VDIM][BATCH]
    P.lf    = ws + (size_t)VDIM * BATCH;               // [VDIM][BATCH]
    P.score = ws + 2 * (size_t)VDIM * BATCH;           // [BATCH]

    gfn_scan<<<dim3(NBLK), dim3(NT), 0, stream>>>(P);
    gfn_loss<<<dim3(1), dim3(NT), 0, stream>>>(P);
}

// Round 4
// 4537.745 us; speedup vs baseline: 6.5514x; 6.5514x over previous
//
#include <hip/hip_runtime.h>
#include <hip/hip_bf16.h>
#include <math.h>

#define VDIM 128
#define HDIM 512
#define BATCH 512
#define RPB 4                  // batch rows per scan block
#define NBLK (BATCH / RPB)     // 128 scan blocks
#define NT 512                 // scan threads (8 waves)
#define LN_EPS 1e-5f

#define FNT 256                // fnet threads (4 waves)
#define FROWS 16               // fnet rows per tile
#define FRG (BATCH / FROWS)    // 32 row groups
#define FGRID (VDIM * FRG)     // 4096 fnet blocks

// ---------- float4 helpers ----------
__device__ __forceinline__ float4 f4zero() { return make_float4(0.f, 0.f, 0.f, 0.f); }
__device__ __forceinline__ float4 f4add(float4 a, float4 b) {
    return make_float4(a.x + b.x, a.y + b.y, a.z + b.z, a.w + b.w);
}
__device__ __forceinline__ float4 f4fma(float4 a, float s, float4 c) {
    return make_float4(fmaf(a.x, s, c.x), fmaf(a.y, s, c.y),
                       fmaf(a.z, s, c.z), fmaf(a.w, s, c.w));
}
__device__ __forceinline__ float4 f4scale(float4 a, float s) {
    return make_float4(a.x * s, a.y * s, a.z * s, a.w * s);
}
__device__ __forceinline__ float4 f4sub(float4 a, float4 b) {
    return make_float4(a.x - b.x, a.y - b.y, a.z - b.z, a.w - b.w);
}
__device__ __forceinline__ float f4get(float4 v, int r) {
    return r == 0 ? v.x : r == 1 ? v.y : r == 2 ? v.z : v.w;
}

struct Params {
    const float *u;
    const float *q_w1, *q_b1, *q_g1, *q_be1;
    const float *q_w2, *q_b2, *q_g2, *q_be2;
    const float *q_w3, *q_b3, *q_g3, *q_be3;
    const float *q_W, *q_bias, *q_marg;
    const float *f_w1, *f_b1, *f_g1, *f_be1;
    const float *f_w2, *f_b2, *f_g2, *f_be2;
    const float *f_w3, *f_b3, *f_g3, *f_be3;
    const float *f_w4, *f_b4, *J;
    const int *top_order, *pa_mask;
    float *V_out, *lp, *lf, *score, *vs, *loss;
};

// block-wide (512 thr) deterministic float4 allreduce
__device__ __forceinline__ float4 allreduce4(float4 v, float4 *red4, int tid) {
#pragma unroll
    for (int off = 1; off < 64; off <<= 1) {
        v.x += __shfl_xor(v.x, off, 64);
        v.y += __shfl_xor(v.y, off, 64);
        v.z += __shfl_xor(v.z, off, 64);
        v.w += __shfl_xor(v.w, off, 64);
    }
    if ((tid & 63) == 0) red4[tid >> 6] = v;
    __syncthreads();
    float4 s = red4[0];
#pragma unroll
    for (int w = 1; w < 8; ++w) s = f4add(s, red4[w]);
    __syncthreads();
    return s;
}

__device__ __forceinline__ float block_reduce1(float v, float *red, int tid) {
#pragma unroll
    for (int off = 1; off < 64; off <<= 1) v += __shfl_xor(v, off, 64);
    if ((tid & 63) == 0) red[tid >> 6] = v;
    __syncthreads();
    float s = 0.f;
#pragma unroll
    for (int w = 0; w < 8; ++w) s += red[w];
    __syncthreads();
    return s;
}

// ---------------- scan GEMV+LN: 4 rows via AT layout, 4-way K-split ----------------
// inAT[k] = float4 of 4 rows' activation at k. W: [K][HDIM] row-major.
// Thread (ks=tid>>7, cq=tid&127): cols 4cq..4cq+3, K-chunk ks.
template <int K>
__device__ __forceinline__ void gemv_ln_scan(const float4 *__restrict__ inAT,
                                             const float *__restrict__ W,
                                             const float *__restrict__ bias,
                                             const float *__restrict__ gam,
                                             const float *__restrict__ bet,
                                             float4 *__restrict__ outAT,
                                             float4 *part, float4 *red4,
                                             int tid, int ks, int cq) {
    const int kc = K / 4;
    const float4 *inP = inAT + ks * kc;
    const float4 *Wp = (const float4 *)W + (size_t)(ks * kc) * (HDIM / 4) + cq;
    float4 a0 = f4zero(), a1 = f4zero(), a2 = f4zero(), a3 = f4zero();
#pragma unroll 8
    for (int k = 0; k < kc; ++k) {
        float4 a = inP[k];                         // LDS b128 broadcast
        float4 w = Wp[(size_t)k * (HDIM / 4)];     // 1KB/wave coalesced
        a0 = f4fma(a, w.x, a0);
        a1 = f4fma(a, w.y, a1);
        a2 = f4fma(a, w.z, a2);
        a3 = f4fma(a, w.w, a3);
    }
    float4 *my = part + tid * 4;
    my[0] = a0; my[1] = a1; my[2] = a2; my[3] = a3;
    __syncthreads();
    float4 rowsum = f4zero();
    if (ks == 0) {
#pragma unroll
        for (int s = 1; s < 4; ++s) {
            const float4 *ps = part + (s * 128 + cq) * 4;
            a0 = f4add(a0, ps[0]);
            a1 = f4add(a1, ps[1]);
            a2 = f4add(a2, ps[2]);
            a3 = f4add(a3, ps[3]);
        }
        float4 b4 = ((const float4 *)bias)[cq];
        a0.x += b4.x; a0.y += b4.x; a0.z += b4.x; a0.w += b4.x;
        a1.x += b4.y; a1.y += b4.y; a1.z += b4.y; a1.w += b4.y;
        a2.x += b4.z; a2.y += b4.z; a2.z += b4.z; a2.w += b4.z;
        a3.x += b4.w; a3.y += b4.w; a3.z += b4.w; a3.w += b4.w;
        rowsum = f4add(f4add(a0, a1), f4add(a2, a3));
    }
    const float inv = 1.f / (float)HDIM;
    float4 m4 = f4scale(allreduce4(rowsum, red4, tid), inv);
    float4 d0, d1, d2, d3, sq = f4zero();
    if (ks == 0) {
        d0 = f4sub(a0, m4); d1 = f4sub(a1, m4);
        d2 = f4sub(a2, m4); d3 = f4sub(a3, m4);
        sq.x = d0.x * d0.x + d1.x * d1.x + d2.x * d2.x + d3.x * d3.x;
        sq.y = d0.y * d0.y + d1.y * d1.y + d2.y * d2.y + d3.y * d3.y;
        sq.z = d0.z * d0.z + d1.z * d1.z + d2.z * d2.z + d3.z * d3.z;
        sq.w = d0.w * d0.w + d1.w * d1.w + d2.w * d2.w + d3.w * d3.w;
    }
    float4 var = f4scale(allreduce4(sq, red4, tid), inv);
    if (ks == 0) {
        float4 rs;
        rs.x = 1.f / sqrtf(var.x + LN_EPS);
        rs.y = 1.f / sqrtf(var.y + LN_EPS);
        rs.z = 1.f / sqrtf(var.z + LN_EPS);
        rs.w = 1.f / sqrtf(var.w + LN_EPS);
        float4 g4 = ((const float4 *)gam)[cq];
        float4 e4 = ((const float4 *)bet)[cq];
        float4 h;
        h.x = fmaxf(fmaf(d0.x * rs.x, g4.x, e4.x), 0.f);
        h.y = fmaxf(fmaf(d0.y * rs.y, g4.x, e4.x), 0.f);
        h.z = fmaxf(fmaf(d0.z * rs.z, g4.x, e4.x), 0.f);
        h.w = fmaxf(fmaf(d0.w * rs.w, g4.x, e4.x), 0.f);
        outAT[4 * cq + 0] = h;
        h.x = fmaxf(fmaf(d1.x * rs.x, g4.y, e4.y), 0.f);
        h.y = fmaxf(fmaf(d1.y * rs.y, g4.y, e4.y), 0.f);
        h.z = fmaxf(fmaf(d1.z * rs.z, g4.y, e4.y), 0.f);
        h.w = fmaxf(fmaf(d1.w * rs.w, g4.y, e4.y), 0.f);
        outAT[4 * cq + 1] = h;
        h.x = fmaxf(fmaf(d2.x * rs.x, g4.z, e4.z), 0.f);
        h.y = fmaxf(fmaf(d2.y * rs.y, g4.z, e4.z), 0.f);
        h.z = fmaxf(fmaf(d2.z * rs.z, g4.z, e4.z), 0.f);
        h.w = fmaxf(fmaf(d2.w * rs.w, g4.z, e4.z), 0.f);
        outAT[4 * cq + 2] = h;
        h.x = fmaxf(fmaf(d3.x * rs.x, g4.w, e4.w), 0.f);
        h.y = fmaxf(fmaf(d3.y * rs.y, g4.w, e4.w), 0.f);
        h.z = fmaxf(fmaf(d3.z * rs.z, g4.w, e4.w), 0.f);
        h.w = fmaxf(fmaf(d3.w * rs.w, g4.w, e4.w), 0.f);
        outAT[4 * cq + 3] = h;
    }
    __syncthreads();
}

// ---------------- sequential scan: qtrunk + sampling only ----------------
__global__ __launch_bounds__(NT) void gfn_scan(Params P) {
    __shared__ float4 VT[VDIM];        // V^T: [col] -> 4 rows
    __shared__ float4 VPT[VDIM];
    __shared__ float4 ATa[HDIM];
    __shared__ float4 ATb[HDIM];
    __shared__ float4 part[4 * 128 * 4];   // 32KB K-split partials
    __shared__ float4 red4[8];

    const int tid = threadIdx.x;
    const int ks = tid >> 7;
    const int cq = tid & 127;
    const int row0 = blockIdx.x * RPB;

    if (tid < VDIM) VT[tid] = f4zero();
    __syncthreads();

    for (int i = 0; i < VDIM; ++i) {
        const int node = P.top_order[i];

        float4 ap = f4zero();
        if (tid < VDIM) {
            float mk = (float)P.pa_mask[node * VDIM + tid];
            float4 v = VT[tid];
            float4 vp = f4scale(v, mk);
            VPT[tid] = vp;
            ap = make_float4(fabsf(vp.x), fabsf(vp.y), fabsf(vp.z), fabsf(vp.w));
        }
        float4 asum = allreduce4(ap, red4, tid);   // barrier also publishes VPT

        gemv_ln_scan<VDIM>(VPT, P.q_w1, P.q_b1, P.q_g1, P.q_be1, ATa, part, red4, tid, ks, cq);
        gemv_ln_scan<HDIM>(ATa, P.q_w2, P.q_b2, P.q_g2, P.q_be2, ATb, part, red4, tid, ks, cq);
        gemv_ln_scan<HDIM>(ATb, P.q_w3, P.q_b3, P.q_g3, P.q_be3, ATa, part, red4, tid, ks, cq);

        // head: x[r] = sum_c h3[r][c] * q_W[node][c]
        float4 xp = f4zero();
        if (tid < 128) {
            float4 wq = ((const float4 *)(P.q_W + (size_t)node * HDIM))[tid];
            xp = f4fma(ATa[4 * tid + 0], wq.x, xp);
            xp = f4fma(ATa[4 * tid + 1], wq.y, xp);
            xp = f4fma(ATa[4 * tid + 2], wq.z, xp);
            xp = f4fma(ATa[4 * tid + 3], wq.w, xp);
        }
        float4 x4 = allreduce4(xp, red4, tid);

        if (tid < RPB) {
            const int r = tid;
            float asr = f4get(asum, r);
            float xr = f4get(x4, r) + P.q_bias[node];
            float arg = (asr == 0.f) ? P.q_marg[node] : xr;
            float p = 1.f / (1.f + expf(-arg));
            float uv = P.u[i * BATCH + row0 + r];
            bool samp = uv < p;
            float v = samp ? 1.f : -1.f;
            ((float *)&VT[node])[r] = v;
            P.vs[i * BATCH + row0 + r] = v;
            P.lp[i * BATCH + row0 + r] = samp ? logf(p) : log1pf(-p);
        }
        __syncthreads();
    }

    // terminal score
    float4 inner = f4zero();
    if (tid < 128) {
#pragma unroll 4
        for (int ii = 0; ii < VDIM; ++ii)
            inner = f4fma(VT[ii], P.J[(size_t)ii * VDIM + tid], inner);
        float4 vc = VT[tid];
        inner = make_float4(inner.x * vc.x, inner.y * vc.y, inner.z * vc.z, inner.w * vc.w);
    }
    float4 sc4 = allreduce4(inner, red4, tid);
    if (tid < RPB) P.score[row0 + tid] = f4get(sc4, tid);
    if (tid < VDIM) {
        float4 v = VT[tid];
        P.V_out[(size_t)(row0 + 0) * VDIM + tid] = v.x;
        P.V_out[(size_t)(row0 + 1) * VDIM + tid] = v.y;
        P.V_out[(size_t)(row0 + 2) * VDIM + tid] = v.z;
        P.V_out[(size_t)(row0 + 3) * VDIM + tid] = v.w;
    }
}

// ---------------- batched fnet ----------------
// 4-wave reduce of 8 per-row partials across the 128 threads of a row-half.
__device__ __forceinline__ void reduce8_256(float4 &a, float4 &b,
                                            float4 *redA, float4 *redB, int tid) {
#pragma unroll
    for (int off = 1; off < 64; off <<= 1) {
        a.x += __shfl_xor(a.x, off, 64); a.y += __shfl_xor(a.y, off, 64);
        a.z += __shfl_xor(a.z, off, 64); a.w += __shfl_xor(a.w, off, 64);
        b.x += __shfl_xor(b.x, off, 64); b.y += __shfl_xor(b.y, off, 64);
        b.z += __shfl_xor(b.z, off, 64); b.w += __shfl_xor(b.w, off, 64);
    }
    int w = tid >> 6;
    if ((tid & 63) == 0) { redA[w] = a; redB[w] = b; }
    __syncthreads();
    int p = w ^ 1;
    a = f4add(redA[w], redA[p]);
    b = f4add(redB[w], redB[p]);
    __syncthreads();
}

// One fnet layer on a 16-row tile. in: LDS col-major [c][16]; out may equal in.
// Thread (rh=tid>>7 -> rows 8rh..8rh+7, cq=tid&127 -> cols 4cq..4cq+3).
template <int K>
__device__ __forceinline__ void flayer(const float *__restrict__ in,
                                       const float *__restrict__ W,
                                       const float *__restrict__ bias,
                                       const float *__restrict__ gam,
                                       const float *__restrict__ bet,
                                       float *__restrict__ out,
                                       float4 *redA, float4 *redB, int tid) {
    const int rh = tid >> 7, cq = tid & 127;
    const float4 *Wv = (const float4 *)W + cq;
    float4 accA[4], accB[4];
#pragma unroll
    for (int j = 0; j < 4; ++j) { accA[j] = f4zero(); accB[j] = f4zero(); }
#pragma unroll 4
    for (int k = 0; k < K; ++k) {
        float4 w = Wv[(size_t)k * (HDIM / 4)];
        const float *ip = in + k * FROWS + 8 * rh;
        float4 aA = *(const float4 *)ip;
        float4 aB = *(const float4 *)(ip + 4);
        accA[0] = f4fma(aA, w.x, accA[0]); accB[0] = f4fma(aB, w.x, accB[0]);
        accA[1] = f4fma(aA, w.y, accA[1]); accB[1] = f4fma(aB, w.y, accB[1]);
        accA[2] = f4fma(aA, w.z, accA[2]); accB[2] = f4fma(aB, w.z, accB[2]);
        accA[3] = f4fma(aA, w.w, accA[3]); accB[3] = f4fma(aB, w.w, accB[3]);
    }
    float4 b4 = ((const float4 *)bias)[cq];
    float bb[4] = {b4.x, b4.y, b4.z, b4.w};
#pragma unroll
    for (int j = 0; j < 4; ++j) {
        accA[j].x += bb[j]; accA[j].y += bb[j]; accA[j].z += bb[j]; accA[j].w += bb[j];
        accB[j].x += bb[j]; accB[j].y += bb[j]; accB[j].z += bb[j]; accB[j].w += bb[j];
    }
    const float inv = 1.f / (float)HDIM;
    float4 sA = f4add(f4add(accA[0], accA[1]), f4add(accA[2], accA[3]));
    float4 sB = f4add(f4add(accB[0], accB[1]), f4add(accB[2], accB[3]));
    reduce8_256(sA, sB, redA, redB, tid);
    float4 mA = f4scale(sA, inv), mB = f4scale(sB, inv);
    float4 dA[4], dB[4];
    float4 qA = f4zero(), qB = f4zero();
#pragma unroll
    for (int j = 0; j < 4; ++j) {
        dA[j] = f4sub(accA[j], mA);
        dB[j] = f4sub(accB[j], mB);
        qA.x += dA[j].x * dA[j].x; qA.y += dA[j].y * dA[j].y;
        qA.z += dA[j].z * dA[j].z; qA.w += dA[j].w * dA[j].w;
        qB.x += dB[j].x * dB[j].x; qB.y += dB[j].y * dB[j].y;
        qB.z += dB[j].z * dB[j].z; qB.w += dB[j].w * dB[j].w;
    }
    reduce8_256(qA, qB, redA, redB, tid);
    float4 rsA, rsB;
    rsA.x = 1.f / sqrtf(qA.x * inv + LN_EPS); rsA.y = 1.f / sqrtf(qA.y * inv + LN_EPS);
    rsA.z = 1.f / sqrtf(qA.z * inv + LN_EPS); rsA.w = 1.f / sqrtf(qA.w * inv + LN_EPS);
    rsB.x = 1.f / sqrtf(qB.x * inv + LN_EPS); rsB.y = 1.f / sqrtf(qB.y * inv + LN_EPS);
    rsB.z = 1.f / sqrtf(qB.z * inv + LN_EPS); rsB.w = 1.f / sqrtf(qB.w * inv + LN_EPS);
    float4 g4 = ((const float4 *)gam)[cq];
    float4 e4 = ((const float4 *)bet)[cq];
    float gg[4] = {g4.x, g4.y, g4.z, g4.w};
    float ee[4] = {e4.x, e4.y, e4.z, e4.w};
    // all reads of `in` completed before reduce8's barriers -> safe to overwrite
#pragma unroll
    for (int j = 0; j < 4; ++j) {
        float4 hA, hB;
        hA.x = fmaxf(fmaf(dA[j].x * rsA.x, gg[j], ee[j]), 0.f);
        hA.y = fmaxf(fmaf(dA[j].y * rsA.y, gg[j], ee[j]), 0.f);
        hA.z = fmaxf(fmaf(dA[j].z * rsA.z, gg[j], ee[j]), 0.f);
        hA.w = fmaxf(fmaf(dA[j].w * rsA.w, gg[j], ee[j]), 0.f);
        hB.x = fmaxf(fmaf(dB[j].x * rsB.x, gg[j], ee[j]), 0.f);
        hB.y = fmaxf(fmaf(dB[j].y * rsB.y, gg[j], ee[j]), 0.f);
        hB.z = fmaxf(fmaf(dB[j].z * rsB.z, gg[j], ee[j]), 0.f);
        hB.w = fmaxf(fmaf(dB[j].w * rsB.w, gg[j], ee[j]), 0.f);
        float *op = out + (4 * cq + j) * FROWS + 8 * rh;
        *(float4 *)op = hA;
        *(float4 *)(op + 4) = hB;
    }
    __syncthreads();
}

__global__ __launch_bounds__(FNT) void gfn_fnet(Params P) {
    __shared__ float Vt[VDIM * FROWS];     // 8KB  [k][16]
    __shared__ float A[HDIM * FROWS];      // 32KB [c][16]
    __shared__ int ord[VDIM];
    __shared__ int invp[VDIM];
    __shared__ float4 redA[4], redB[4];

    const int tid = threadIdx.x;
    const int t = blockIdx.x >> 5;             // step 0..127
    const int r0 = (blockIdx.x & 31) * FROWS;  // row offset

    if (tid < VDIM) ord[tid] = P.top_order[tid];
    __syncthreads();
    if (tid < VDIM) invp[ord[tid]] = tid;
    __syncthreads();
    for (int idx = tid; idx < VDIM * FROWS; idx += FNT) {
        int k = idx >> 4, row = idx & 15;
        int s = invp[k];
        Vt[idx] = (s <= t) ? P.vs[s * BATCH + r0 + row] : 0.f;
    }
    __syncthreads();

    flayer<VDIM>(Vt, P.f_w1, P.f_b1, P.f_g1, P.f_be1, A, redA, redB, tid);
    flayer<HDIM>(A, P.f_w2, P.f_b2, P.f_g2, P.f_be2, A, redA, redB, tid);
    flayer<HDIM>(A, P.f_w3, P.f_b3, P.f_g3, P.f_be3, A, redA, redB, tid);

    const int rh = tid >> 7, cq = tid & 127;
    float4 w4 = ((const float4 *)P.f_w4)[cq];
    float ww[4] = {w4.x, w4.y, w4.z, w4.w};
    float4 sA = f4zero(), sB = f4zero();
#pragma unroll
    for (int j = 0; j < 4; ++j) {
        const float *ap = A + (4 * cq + j) * FROWS + 8 * rh;
        float4 aA = *(const float4 *)ap;
        float4 aB = *(const float4 *)(ap + 4);
        sA = f4fma(aA, ww[j], sA);
        sB = f4fma(aB, ww[j], sB);
    }
    reduce8_256(sA, sB, redA, redB, tid);
    if (cq == 0) {
        float b4v = P.f_b4[0];
        float *dst = P.lf + (size_t)t * BATCH + r0 + 8 * rh;
        dst[0] = sA.x + b4v; dst[1] = sA.y + b4v;
        dst[2] = sA.z + b4v; dst[3] = sA.w + b4v;
        dst[4] = sB.x + b4v; dst[5] = sB.y + b4v;
        dst[6] = sB.z + b4v; dst[7] = sB.w + b4v;
    }
}

// ---------------- loss ----------------
__global__ __launch_bounds__(NT) void gfn_loss(Params P) {
    __shared__ float H1[HDIM], H2[HDIM];
    __shared__ float red1[8];
    const int tid = threadIdx.x;
    const float inv = 1.f / (float)HDIM;

    float z = P.f_b1[tid];
    float m = block_reduce1(z, red1, tid) * inv;
    float d = z - m;
    float var = block_reduce1(d * d, red1, tid) * inv;
    float h = fmaxf(fmaf(d * (1.f / sqrtf(var + LN_EPS)), P.f_g1[tid], P.f_be1[tid]), 0.f);
    H1[tid] = h;
    __syncthreads();

    float acc = 0.f;
    for (int k = 0; k < HDIM; ++k) acc = fmaf(H1[k], P.f_w2[(size_t)k * HDIM + tid], acc);
    z = acc + P.f_b2[tid];
    m = block_reduce1(z, red1, tid) * inv;
    d = z - m;
    var = block_reduce1(d * d, red1, tid) * inv;
    h = fmaxf(fmaf(d * (1.f / sqrtf(var + LN_EPS)), P.f_g2[tid], P.f_be2[tid]), 0.f);
    H2[tid] = h;
    __syncthreads();

    acc = 0.f;
    for (int k = 0; k < HDIM; ++k) acc = fmaf(H2[k], P.f_w3[(size_t)k * HDIM + tid], acc);
    z = acc + P.f_b3[tid];
    m = block_reduce1(z, red1, tid) * inv;
    d = z - m;
    var = block_reduce1(d * d, red1, tid) * inv;
    h = fmaxf(fmaf(d * (1.f / sqrtf(var + LN_EPS)), P.f_g3[tid], P.f_be3[tid]), 0.f);
    float F0 = block_reduce1(h * P.f_w4[tid], red1, tid) + P.f_b4[0];

    const int b = tid;
    float lfp = F0;
    float s = 0.f;
    for (int t = 0; t < VDIM; ++t) {
        float lp = P.lp[t * BATCH + b];
        float lfn = (t == VDIM - 1) ? P.score[b] : P.lf[t * BATCH + b];
        float dd = lfp + lp - lfn;
        s = fmaf(dd, dd, s);
        lfp = lfn;
    }
    s *= (1.f / (float)VDIM);
    float total = block_reduce1(s, red1, tid) * (1.f / (float)BATCH);
    if (tid == 0) P.loss[0] = total;
}

extern "C" void kernel_launch(void *const *d_in, const int *in_sizes, int n_in,
                              void *d_out, int out_size, void *d_ws, size_t ws_size,
                              hipStream_t stream) {
    Params P;
    P.u     = (const float *)d_in[0];
    P.q_w1  = (const float *)d_in[1];
    P.q_b1  = (const float *)d_in[2];
    P.q_g1  = (const float *)d_in[3];
    P.q_be1 = (const float *)d_in[4];
    P.q_w2  = (const float *)d_in[5];
    P.q_b2  = (const float *)d_in[6];
    P.q_g2  = (const float *)d_in[7];
    P.q_be2 = (const float *)d_in[8];
    P.q_w3  = (const float *)d_in[9];
    P.q_b3  = (const float *)d_in[10];
    P.q_g3  = (const float *)d_in[11];
    P.q_be3 = (const float *)d_in[12];
    P.q_W   = (const float *)d_in[13];
    P.q_bias= (const float *)d_in[14];
    P.q_marg= (const float *)d_in[15];
    P.f_w1  = (const float *)d_in[16];
    P.f_b1  = (const float *)d_in[17];
    P.f_g1  = (const float *)d_in[18];
    P.f_be1 = (const float *)d_in[19];
    P.f_w2  = (const float *)d_in[20];
    P.f_b2  = (const float *)d_in[21];
    P.f_g2  = (const float *)d_in[22];
    P.f_be2 = (const float *)d_in[23];
    P.f_w3  = (const float *)d_in[24];
    P.f_b3  = (const float *)d_in[25];
    P.f_g3  = (const float *)d_in[26];
    P.f_be3 = (const float *)d_in[27];
    P.f_w4  = (const float *)d_in[28];
    P.f_b4  = (const float *)d_in[29];
    P.J     = (const float *)d_in[30];
    P.top_order = (const int *)d_in[31];
    P.pa_mask   = (const int *)d_in[32];

    float *ws = (float *)d_ws;
    P.V_out = (float *)d_out;
    P.loss  = (float *)d_out + (size_t)BATCH * VDIM;
    P.lp    = ws;                                       // [128][512]
    P.lf    = ws + (size_t)VDIM * BATCH;                // [128][512]
    P.score = ws + 2 * (size_t)VDIM * BATCH;            // [512]
    P.vs    = ws + 2 * (size_t)VDIM * BATCH + BATCH;    // [128][512]

    gfn_scan<<<dim3(NBLK), dim3(NT), 0, stream>>>(P);
    gfn_fnet<<<dim3(FGRID), dim3(FNT), 0, stream>>>(P);
    gfn_loss<<<dim3(1), dim3(NT), 0, stream>>>(P);
}